// Round 17
// baseline (302.241 us; speedup 1.0000x reference)
//
#include <hip/hip_runtime.h>

#define IMH 480
#define IMW 640
#define HW (IMH*IMW)
#define NB 16
#define QPR (IMW/2)                   // quads per quad-row (320)

// iter_kernel geometry (R12 proven optimum): 100 blocks/batch * 256 thr * 4 px * 3 groups == HW
#define BPB 100
#define TPX 4
#define GROUPS 3
#define THREADS_PB (BPB*256)          // 25600 threads per batch
#define GSTRIDE (THREADS_PB*TPX)      // 102400 px per group = 160 rows
#define GROWS (GSTRIDE/IMW)           // 160

#define MMB 512                        // minmax blocks (atomic-free partials)

// ---- order-preserving float<->uint encoding ----
__device__ inline unsigned fenc(float x){
    unsigned u = __float_as_uint(x);
    return (u & 0x80000000u) ? ~u : (u | 0x80000000u);
}
__device__ inline float fdec(unsigned e){
    unsigned u = (e & 0x80000000u) ? (e & 0x7FFFFFFFu) : ~e;
    return __uint_as_float(u);
}

// ---- minmax + build d1 quad tiles: unit = one float4 of two adjacent rows -> 2 quads ----
// quad(rp,qc) = {(2rp,2qc),(2rp,2qc+1),(2rp+1,2qc),(2rp+1,2qc+1)} as .x,.y,.z,.w (16-B aligned)
__global__ __launch_bounds__(256) void minmax_kernel(const float* __restrict__ d,
                                                     float* __restrict__ d1q,
                                                     unsigned* __restrict__ pmin,
                                                     unsigned* __restrict__ pmax,
                                                     float* __restrict__ acc){
    if (blockIdx.x == 0){
        for (int k = threadIdx.x; k < NB*27; k += 256) acc[k] = 0.f;
    }
    unsigned lmin = 0xFFFFFFFFu, lmax = 0u;
    const int total = NB*HW/8;                 // row-pair float4 units
    for (int i = blockIdx.x*256 + threadIdx.x; i < total; i += MMB*256){
        int rp   = i / (IMW/4);                // global row-pair (spans batches seamlessly)
        int col4 = i - rp*(IMW/4);
        const float* top = d + (size_t)rp*(2*IMW) + col4*4;
        float4 t = *(const float4*)top;
        float4 bt = *(const float4*)(top + IMW);
        unsigned e0=fenc(t.x),e1=fenc(t.y),e2=fenc(t.z),e3=fenc(t.w);
        unsigned f0=fenc(bt.x),f1=fenc(bt.y),f2=fenc(bt.z),f3=fenc(bt.w);
        lmin = min(lmin, min(min(min(e0,e1),min(e2,e3)), min(min(f0,f1),min(f2,f3))));
        lmax = max(lmax, max(max(max(e0,e1),max(e2,e3)), max(max(f0,f1),max(f2,f3))));
        float* dst = d1q + (size_t)rp*(2*IMW) + col4*8;
        *(float4*)dst       = make_float4(t.x, t.y, bt.x, bt.y);
        *(float4*)(dst + 4) = make_float4(t.z, t.w, bt.z, bt.w);
    }
    #pragma unroll
    for (int off = 32; off; off >>= 1){
        lmin = min(lmin, (unsigned)__shfl_down((int)lmin, off));
        lmax = max(lmax, (unsigned)__shfl_down((int)lmax, off));
    }
    __shared__ unsigned smin[4], smax[4];
    int wave = threadIdx.x >> 6, lane = threadIdx.x & 63;
    if (lane == 0){ smin[wave] = lmin; smax[wave] = lmax; }
    __syncthreads();
    if (threadIdx.x == 0){
        pmin[blockIdx.x] = min(min(smin[0],smin[1]), min(smin[2],smin[3]));
        pmax[blockIdx.x] = max(max(smax[0],smax[1]), max(smax[2],smax[3]));
    }
}

// ---- normal1 packed 3x biased-ubyte into QUAD-TILED layout; 4 px/thread row-wise ----
__global__ __launch_bounds__(256) void normal_kernel(const float* __restrict__ depth1,
                                                     const float* __restrict__ Kp,
                                                     const unsigned* __restrict__ pmin,
                                                     const unsigned* __restrict__ pmax,
                                                     unsigned* __restrict__ nrmq,
                                                     float4* __restrict__ weights4){
    __shared__ unsigned sred[8];
    __shared__ unsigned sfin[2];
    {
        unsigned vmin = min(pmin[threadIdx.x], pmin[threadIdx.x + 256]);
        unsigned vmax = max(pmax[threadIdx.x], pmax[threadIdx.x + 256]);
        #pragma unroll
        for (int off = 32; off; off >>= 1){
            vmin = min(vmin, (unsigned)__shfl_down((int)vmin, off));
            vmax = max(vmax, (unsigned)__shfl_down((int)vmax, off));
        }
        int wave = threadIdx.x >> 6, lane = threadIdx.x & 63;
        if (lane == 0){ sred[wave] = vmin; sred[4+wave] = vmax; }
        __syncthreads();
        if (threadIdx.x == 0){
            sfin[0] = min(min(sred[0],sred[1]), min(sred[2],sred[3]));
            sfin[1] = max(max(sred[4],sred[5]), max(sred[6],sred[7]));
        }
        __syncthreads();
    }
    const float dmin = fdec(sfin[0]), dmax = fdec(sfin[1]);

    const int b = blockIdx.y;
    const int t = blockIdx.x*256 + threadIdx.x;        // 0 .. HW/4-1
    const int gpr = IMW/4;                             // 160 groups per row
    const int r = t / gpr;
    const int c0 = (t - r*gpr)*4;
    const float fx = Kp[b*4+0], fy = Kp[b*4+1], cx = Kp[b*4+2], cy = Kp[b*4+3];
    const float inv_fx = 1.f/fx, inv_fy = 1.f/fy;
    const float* __restrict__ d = depth1 + (size_t)b*HW;
    const int rm = max(r-1,0), rp = min(r+1,IMH-1);

    float wm[6], wc[6], wp[6];
    {
        const float* rowm = d + rm*IMW + c0;
        const float* rowc = d + r *IMW + c0;
        const float* rowp = d + rp*IMW + c0;
        float4 vm = *(const float4*)rowm;
        float4 vc = *(const float4*)rowc;
        float4 vp = *(const float4*)rowp;
        wm[1]=vm.x; wm[2]=vm.y; wm[3]=vm.z; wm[4]=vm.w;
        wc[1]=vc.x; wc[2]=vc.y; wc[3]=vc.z; wc[4]=vc.w;
        wp[1]=vp.x; wp[2]=vp.y; wp[3]=vp.z; wp[4]=vp.w;
        bool hasL = (c0 > 0), hasR = (c0+4 < IMW);
        wm[0] = hasL ? rowm[-1] : vm.x;   wm[5] = hasR ? rowm[4] : vm.w;
        wc[0] = hasL ? rowc[-1] : vc.x;   wc[5] = hasR ? rowc[4] : vc.w;
        wp[0] = hasL ? rowp[-1] : vp.x;   wp[5] = hasR ? rowp[4] : vp.w;
    }
    float pxw[6];
    #pragma unroll
    for (int k=0;k<6;k++){
        int cc = min(max(c0-1+k, 0), IMW-1);
        pxw[k] = ((float)cc - cx)*inv_fx;
    }
    const float pym = ((float)rm - cy)*inv_fy;
    const float pyc = ((float)r  - cy)*inv_fy;
    const float pyp = ((float)rp - cy)*inv_fy;

    unsigned packed[4];
    #pragma unroll
    for (int j=0;j<4;j++){
        float aL = wm[j],  aC = wm[j+1], aR = wm[j+2];
        float bL = wc[j],               bR = wc[j+2];
        float cL = wp[j],  cC = wp[j+1], cR = wp[j+2];
        float pL = pxw[j], pC = pxw[j+1], pR = pxw[j+2];

        float dx0 = (pR*aR - pL*aL) + 2.f*(pR*bR - pL*bL) + (pR*cR - pL*cL);
        float dx1 = pym*(aR - aL) + 2.f*pyc*(bR - bL) + pyp*(cR - cL);
        float dx2 = (aR - aL) + 2.f*(bR - bL) + (cR - cL);
        float dy0 = pL*(cL - aL) + 2.f*pC*(cC - aC) + pR*(cR - aR);
        float dy1 = (pyp*cL - pym*aL) + 2.f*(pyp*cC - pym*aC) + (pyp*cR - pym*aR);
        float dy2 = (cL - aL) + 2.f*(cC - aC) + (cR - aR);

        float nx = dx1*dy2 - dx2*dy1;
        float ny = dx2*dy0 - dx0*dy2;
        float nz = dx0*dy1 - dx1*dy0;
        float mag = sqrtf(nx*nx + ny*ny + nz*nz + 1e-16f);
        float inv = __builtin_amdgcn_rcpf(mag + 1e-8f);
        nx *= inv; ny *= inv; nz *= inv;

        float dc = wc[j+1];
        if (dc == dmin || dc == dmax){ nx = 0.f; ny = 0.f; nz = 0.f; }

        int qx = (int)rintf(nx*127.f) + 127;
        int qy = (int)rintf(ny*127.f) + 127;
        int qz = (int)rintf(nz*127.f) + 127;
        packed[j] = ((unsigned)qx) | ((unsigned)qy << 8) | ((unsigned)qz << 16);
    }

    // quad-tiled store: quads (r>>1, c0/2) and (r>>1, c0/2+1), row slot (r&1)
    // dword base = b*HW + (r>>1)*(2*IMW) + (c0>>1)*4 + (r&1)*2  (8-B aligned)
    size_t qb = (size_t)b*HW + (size_t)(r>>1)*(2*IMW) + (size_t)(c0>>1)*4 + (size_t)(r&1)*2;
    *(uint2*)(nrmq + qb)     = make_uint2(packed[0], packed[1]);
    *(uint2*)(nrmq + qb + 4) = make_uint2(packed[2], packed[3]);

    size_t o4 = (size_t)b*(HW/4) + (size_t)r*gpr + (c0>>2);
    weights4[o4] = make_float4(1.f,1.f,1.f,1.f);
}

// ---- per-pixel ICP; quad-tiled gathers: avg 4.5 aligned dwordx4 per px vs 8 dword ----
__global__ __launch_bounds__(256) void iter_kernel(const float4* __restrict__ depth0_v4,
                                                   const float4* __restrict__ d1q,
                                                   const uint4* __restrict__ nrmq,
                                                   const float* __restrict__ Kp,
                                                   const float* __restrict__ stateR,
                                                   const float* __restrict__ statet,
                                                   float* __restrict__ acc){
    const int b = blockIdx.y;
    const float fx = Kp[b*4+0], fy = Kp[b*4+1], cx = Kp[b*4+2], cy = Kp[b*4+3];
    const float inv_fx = 1.f/fx, inv_fy = 1.f/fy;
    float Rm[9];
    #pragma unroll
    for (int i=0;i<9;i++) Rm[i] = stateR[b*9+i];
    float tv[3];
    #pragma unroll
    for (int i=0;i<3;i++) tv[i] = statet[b*3+i];

    const float4* __restrict__ d0v = depth0_v4 + (size_t)b*(HW/4);
    const float4* __restrict__ dq  = d1q + (size_t)b*(HW/4);
    const uint4*  __restrict__ nq  = nrmq + (size_t)b*(HW/4);

    float accv[27];
    #pragma unroll
    for (int i=0;i<27;i++) accv[i] = 0.f;

    const int tid = blockIdx.x*256 + threadIdx.x;     // 0..25599
    const int base0 = tid*TPX;
    const int c0 = base0 % IMW;
    const int r0 = base0 / IMW;
    const float px_base = ((float)c0 - cx)*inv_fx;
    const float py0 = ((float)r0 - cy)*inv_fy;
    const float py_step = (float)GROWS*inv_fy;
    const float inv127 = 1.f/127.f;

    #pragma unroll
    for (int g = 0; g < GROUPS; g++){
        float4 d4 = d0v[tid + g*THREADS_PB];
        float dd[4] = {d4.x, d4.y, d4.z, d4.w};
        float pyv = py0 + (float)g*py_step;

        #pragma unroll
        for (int j = 0; j < TPX; j++){
            float d0 = dd[j];
            float V0x = (px_base + (float)j*inv_fx)*d0;
            float V0y = pyv*d0;
            float V0z = d0;

            float X = Rm[0]*V0x + Rm[1]*V0y + Rm[2]*V0z + tv[0];
            float Y = Rm[3]*V0x + Rm[4]*V0y + Rm[5]*V0z + tv[1];
            float Z = Rm[6]*V0x + Rm[7]*V0y + Rm[8]*V0z + tv[2];
            float invZ = __builtin_amdgcn_rcpf(Z);
            float uu = X*invZ*fx + cx;
            float vv = Y*invZ*fy + cy;

            bool inview = (uu > 0.f) && (uu < (float)(IMW-1)) && (vv > 0.f) && (vv < (float)(IMH-1));

            float J0=0.f,J1=0.f,J2=0.f,J3=0.f,J4=0.f,J5=0.f,wres=0.f;
            if (inview){
                float u0f = floorf(uu), v0f = floorf(vv);
                int u0 = (int)u0f, v0 = (int)v0f;
                float wu = uu - u0f, wv = vv - v0f;
                float w00 = (1.f-wu)*(1.f-wv), w10 = wu*(1.f-wv), w01 = (1.f-wu)*wv, w11 = wu*wv;

                int u0h = u0 >> 1, aq = u0 & 1;
                int v0h = v0 >> 1, bq = v0 & 1;
                int qi = v0h*QPR + u0h;

                // depth quads (predicated aligned dwordx4 loads)
                float4 D00 = dq[qi];
                float4 DR = D00, DD = D00;
                if (aq) DR = dq[qi+1];
                if (bq) DD = dq[qi+QPR];
                float4 DRD = aq ? DR : DD;
                if (aq & bq) DRD = dq[qi+QPR+1];

                float d00 = bq ? (aq ? D00.w : D00.z) : (aq ? D00.y : D00.x);
                float d10 = aq ? (bq ? DR.z : DR.x)   : (bq ? D00.w : D00.y);
                float d01 = bq ? (aq ? DD.y : DD.x)   : (aq ? D00.w : D00.z);
                float d11 = bq ? (aq ? DRD.x : DD.y)  : (aq ? DR.z : D00.w);

                // normal quads
                uint4 N00 = nq[qi];
                uint4 NR = N00, ND = N00;
                if (aq) NR = nq[qi+1];
                if (bq) ND = nq[qi+QPR];
                uint4 NRD = aq ? NR : ND;
                if (aq & bq) NRD = nq[qi+QPR+1];

                unsigned h00 = bq ? (aq ? N00.w : N00.z) : (aq ? N00.y : N00.x);
                unsigned h10 = aq ? (bq ? NR.z : NR.x)   : (bq ? N00.w : N00.y);
                unsigned h01 = bq ? (aq ? ND.y : ND.x)   : (aq ? N00.w : N00.z);
                unsigned h11 = bq ? (aq ? NRD.x : ND.y)  : (aq ? NR.z : N00.w);

                float pxa = (u0f - cx)*inv_fx, pxb = pxa + inv_fx;
                float pya = (v0f - cy)*inv_fy, pyb = pya + inv_fy;
                float a = w00*d00, bb = w10*d10, cc = w01*d01, ee = w11*d11;
                float rVz = (a + bb) + (cc + ee);
                float rVx = (a + cc)*pxa + (bb + ee)*pxb;
                float rVy = (a + bb)*pya + (cc + ee)*pyb;

                float q00x = (float)(h00 & 0xFFu);
                float q00y = (float)((h00 >> 8) & 0xFFu);
                float q00z = (float)((h00 >> 16) & 0xFFu);
                float q10x = (float)(h10 & 0xFFu);
                float q10y = (float)((h10 >> 8) & 0xFFu);
                float q10z = (float)((h10 >> 16) & 0xFFu);
                float q01x = (float)(h01 & 0xFFu);
                float q01y = (float)((h01 >> 8) & 0xFFu);
                float q01z = (float)((h01 >> 16) & 0xFFu);
                float q11x = (float)(h11 & 0xFFu);
                float q11y = (float)((h11 >> 8) & 0xFFu);
                float q11z = (float)((h11 >> 16) & 0xFFu);

                float n0x = ((w00*q00x + w10*q10x + w01*q01x + w11*q11x) - 127.f) * inv127;
                float n0y = ((w00*q00y + w10*q10y + w01*q01y + w11*q11y) - 127.f) * inv127;
                float n0z = ((w00*q00z + w10*q10z + w01*q01z + w11*q11z) - 127.f) * inv127;

                float dfx = X - rVx, dfy = Y - rVy, dfz = Z - rVz;
                float d2 = dfx*dfx + dfy*dfy + dfz*dfz + 1e-16f;
                if (d2 <= 0.01f){
                    float res = n0x*dfx + n0y*dfy + n0z*dfz;
                    float N0 = n0x*Rm[0] + n0y*Rm[3] + n0z*Rm[6];
                    float N1 = n0x*Rm[1] + n0y*Rm[4] + n0z*Rm[7];
                    float N2 = n0x*Rm[2] + n0y*Rm[5] + n0z*Rm[8];
                    float cr0 = N1*V0z - N2*V0y;
                    float cr1 = N2*V0x - N0*V0z;
                    float cr2 = N0*V0y - N1*V0x;
                    float ndot = fabsf(N2);
                    float dsh = d0 - 0.4f;
                    float sigz = 0.0012f + 0.0019f*dsh*dsh;
                    float sigma = ndot*sigz + 0.001f;
                    float invs = __builtin_amdgcn_rcpf(sigma + 1e-8f);
                    wres = res*invs;
                    J0 = -cr0*invs; J1 = -cr1*invs; J2 = -cr2*invs;
                    J3 =  N0*invs;  J4 =  N1*invs;  J5 =  N2*invs;
                }
            }

            float Jv[6] = {J0,J1,J2,J3,J4,J5};
            int idx = 0;
            #pragma unroll
            for (int k=0;k<6;k++)
                #pragma unroll
                for (int l=k;l<6;l++){ accv[idx] += Jv[k]*Jv[l]; idx++; }
            #pragma unroll
            for (int k=0;k<6;k++){ accv[idx] += Jv[k]*wres; idx++; }
        }
    }

    #pragma unroll
    for (int i=0;i<27;i++){
        float v = accv[i];
        #pragma unroll
        for (int off=32; off; off >>= 1) v += __shfl_down(v, off);
        accv[i] = v;
    }

    __shared__ float sacc[4][27];
    int wave = threadIdx.x >> 6, lane = threadIdx.x & 63;
    if (lane == 0){
        #pragma unroll
        for (int i=0;i<27;i++) sacc[wave][i] = accv[i];
    }
    __syncthreads();
    if (threadIdx.x < 27){
        float s = sacc[0][threadIdx.x] + sacc[1][threadIdx.x]
                + sacc[2][threadIdx.x] + sacc[3][threadIdx.x];
        atomicAdd(&acc[b*27 + threadIdx.x], s);
    }
}

// ---- per-batch 6x6 solve (f32 Cholesky) + twist update; prevR/prevT parameterized ----
__global__ void solve_kernel(float* __restrict__ acc,
                             const float* __restrict__ prevR, const float* __restrict__ prevT,
                             float* __restrict__ stateR, float* __restrict__ statet,
                             float* __restrict__ outR, float* __restrict__ outt){
    int b = threadIdx.x;
    if (b >= NB) return;

    float a27[27];
    #pragma unroll
    for (int i=0;i<27;i++) a27[i] = acc[b*27+i];
    #pragma unroll
    for (int i=0;i<27;i++) acc[b*27+i] = 0.f;

    float A[6][6], rhs[6];
    int idx = 0;
    #pragma unroll
    for (int k=0;k<6;k++)
        #pragma unroll
        for (int l=k;l<6;l++){ A[k][l] = a27[idx]; A[l][k] = a27[idx]; idx++; }
    #pragma unroll
    for (int k=0;k<6;k++) rhs[k] = a27[21+k];

    float tr = 0.f;
    #pragma unroll
    for (int k=0;k<6;k++) tr += A[k][k];
    float lm = tr*1e-6f;
    #pragma unroll
    for (int k=0;k<6;k++) A[k][k] += lm;

    float L[6][6];
    #pragma unroll
    for (int i=0;i<6;i++){
        #pragma unroll
        for (int j=0;j<=i;j++){
            float s = A[i][j];
            #pragma unroll
            for (int k=0;k<j;k++) s -= L[i][k]*L[j][k];
            if (i == j) L[i][i] = sqrtf(s);
            else        L[i][j] = s / L[j][j];
        }
    }
    float y[6];
    #pragma unroll
    for (int i=0;i<6;i++){
        float s = rhs[i];
        #pragma unroll
        for (int k=0;k<i;k++) s -= L[i][k]*y[k];
        y[i] = s / L[i][i];
    }
    float xi[6];
    #pragma unroll
    for (int ii=5; ii>=0; ii--){
        float s = y[ii];
        #pragma unroll
        for (int k=ii+1;k<6;k++) s -= L[k][ii]*xi[k];
        xi[ii] = s / L[ii][ii];
    }

    float w0 = -xi[0], w1 = -xi[1], w2 = -xi[2];
    float th = sqrtf(w0*w0 + w1*w1 + w2*w2 + 1e-24f);
    float ith = 1.f/th;
    float kx = w0*ith, ky = w1*ith, kz = w2*ith;
    float s = sinf(th), cm1 = 1.f - cosf(th);
    float dRm[9];
    dRm[0] = 1.f + cm1*(-ky*ky - kz*kz);
    dRm[1] = -s*kz + cm1*(kx*ky);
    dRm[2] =  s*ky + cm1*(kx*kz);
    dRm[3] =  s*kz + cm1*(kx*ky);
    dRm[4] = 1.f + cm1*(-kx*kx - kz*kz);
    dRm[5] = -s*kx + cm1*(ky*kz);
    dRm[6] = -s*ky + cm1*(kx*kz);
    dRm[7] =  s*kx + cm1*(ky*kz);
    dRm[8] = 1.f + cm1*(-kx*kx - ky*ky);

    float dt0 = -(dRm[0]*xi[3] + dRm[1]*xi[4] + dRm[2]*xi[5]);
    float dt1 = -(dRm[3]*xi[3] + dRm[4]*xi[4] + dRm[5]*xi[5]);
    float dt2 = -(dRm[6]*xi[3] + dRm[7]*xi[4] + dRm[8]*xi[5]);

    float Rm[9], tv[3];
    #pragma unroll
    for (int i=0;i<9;i++) Rm[i] = prevR[b*9+i];
    #pragma unroll
    for (int i=0;i<3;i++) tv[i] = prevT[b*3+i];

    float Rn[9];
    #pragma unroll
    for (int i=0;i<3;i++)
        #pragma unroll
        for (int j=0;j<3;j++)
            Rn[i*3+j] = Rm[i*3+0]*dRm[0*3+j] + Rm[i*3+1]*dRm[1*3+j] + Rm[i*3+2]*dRm[2*3+j];
    float tn0 = Rm[0]*dt0 + Rm[1]*dt1 + Rm[2]*dt2 + tv[0];
    float tn1 = Rm[3]*dt0 + Rm[4]*dt1 + Rm[5]*dt2 + tv[1];
    float tn2 = Rm[6]*dt0 + Rm[7]*dt1 + Rm[8]*dt2 + tv[2];

    #pragma unroll
    for (int i=0;i<9;i++){ stateR[b*9+i] = Rn[i]; outR[b*9+i] = Rn[i]; }
    statet[b*3+0] = tn0; outt[b*3+0] = tn0;
    statet[b*3+1] = tn1; outt[b*3+1] = tn1;
    statet[b*3+2] = tn2; outt[b*3+2] = tn2;
}

extern "C" void kernel_launch(void* const* d_in, const int* in_sizes, int n_in,
                              void* d_out, int out_size, void* d_ws, size_t ws_size,
                              hipStream_t stream){
    const float* depth0 = (const float*)d_in[0];
    const float* depth1 = (const float*)d_in[1];
    const float* Kp     = (const float*)d_in[2];
    const float* Rin    = (const float*)d_in[3];
    const float* tin    = (const float*)d_in[4];

    float* out     = (float*)d_out;
    float* outR    = out;
    float* outt    = out + NB*9;
    float* weights = out + NB*12;

    unsigned* nrmq = (unsigned*)d_ws;                     // NB*HW dwords, quad-tiled (~20 MB)
    float* d1q     = (float*)(nrmq + (size_t)NB*HW);      // NB*HW floats, quad-tiled (~20 MB)
    unsigned* pmin = (unsigned*)(d1q + (size_t)NB*HW);    // MMB
    unsigned* pmax = pmin + MMB;                          // MMB
    float* stateR  = (float*)(pmax + MMB);                // NB*9
    float* statet  = stateR + NB*9;                       // NB*3
    float* acc     = statet + NB*3;                       // NB*27

    minmax_kernel<<<dim3(MMB), 256, 0, stream>>>(depth1, d1q, pmin, pmax, acc);
    normal_kernel<<<dim3(HW/4/256, NB), 256, 0, stream>>>(depth1, Kp, pmin, pmax, nrmq, (float4*)weights);
    for (int it = 0; it < 3; it++){
        const float* Rsrc = (it == 0) ? Rin : stateR;
        const float* tsrc = (it == 0) ? tin : statet;
        iter_kernel<<<dim3(BPB, NB), 256, 0, stream>>>((const float4*)depth0, (const float4*)d1q, (const uint4*)nrmq,
                                                       Kp, Rsrc, tsrc, acc);
        solve_kernel<<<1, 64, 0, stream>>>(acc, Rsrc, tsrc, stateR, statet, outR, outt);
    }
}

// Round 18
// 226.377 us; speedup vs baseline: 1.3351x; 1.3351x over previous
//
#include <hip/hip_runtime.h>

#define IMH 480
#define IMW 640
#define HW (IMH*IMW)
#define NB 16

// iter_kernel geometry (R12/R16 proven optimum): 100 blocks/batch * 256 thr * 4 px * 3 groups == HW
#define BPB 100
#define TPX 4
#define GROUPS 3
#define THREADS_PB (BPB*256)          // 25600 threads per batch
#define GSTRIDE (THREADS_PB*TPX)      // 102400 px per group = 160 rows
#define GROWS (GSTRIDE/IMW)           // 160

#define MMB 512                        // minmax blocks (atomic-free partials -> no tail penalty)

// ---- order-preserving float<->uint encoding ----
__device__ inline unsigned fenc(float x){
    unsigned u = __float_as_uint(x);
    return (u & 0x80000000u) ? ~u : (u | 0x80000000u);
}
__device__ inline float fdec(unsigned e){
    unsigned u = (e & 0x80000000u) ? (e & 0x7FFFFFFFu) : ~e;
    return __uint_as_float(u);
}

// ---- minmax: per-block partials (no atomics, no init); block 0 also zeros acc ----
__global__ __launch_bounds__(256) void minmax_kernel(const float4* __restrict__ d,
                                                     unsigned* __restrict__ pmin,
                                                     unsigned* __restrict__ pmax,
                                                     float* __restrict__ acc){
    if (blockIdx.x == 0){
        for (int k = threadIdx.x; k < NB*27; k += 256) acc[k] = 0.f;
    }
    unsigned lmin = 0xFFFFFFFFu, lmax = 0u;
    const int total4 = NB*HW/4;
    for (int i = blockIdx.x*256 + threadIdx.x; i < total4; i += MMB*256){
        float4 v = d[i];
        unsigned e0 = fenc(v.x), e1 = fenc(v.y), e2 = fenc(v.z), e3 = fenc(v.w);
        lmin = min(lmin, min(min(e0,e1), min(e2,e3)));
        lmax = max(lmax, max(max(e0,e1), max(e2,e3)));
    }
    #pragma unroll
    for (int off = 32; off; off >>= 1){
        lmin = min(lmin, (unsigned)__shfl_down((int)lmin, off));
        lmax = max(lmax, (unsigned)__shfl_down((int)lmax, off));
    }
    __shared__ unsigned smin[4], smax[4];
    int wave = threadIdx.x >> 6, lane = threadIdx.x & 63;
    if (lane == 0){ smin[wave] = lmin; smax[wave] = lmax; }
    __syncthreads();
    if (threadIdx.x == 0){
        pmin[blockIdx.x] = min(min(smin[0],smin[1]), min(smin[2],smin[3]));
        pmax[blockIdx.x] = max(max(smax[0],smax[1]), max(smax[2],smax[3]));
    }
}

// ---- normal1 packed 3x biased-ubyte; 4 px/thread, vectorized; combines minmax partials ----
__global__ __launch_bounds__(256) void normal_kernel(const float* __restrict__ depth1,
                                                     const float* __restrict__ Kp,
                                                     const unsigned* __restrict__ pmin,
                                                     const unsigned* __restrict__ pmax,
                                                     uint4* __restrict__ nrm4,
                                                     float4* __restrict__ weights4){
    // combine the 512 minmax partials (L2-hot), 2 per thread
    __shared__ unsigned sred[8];
    __shared__ unsigned sfin[2];
    {
        unsigned vmin = min(pmin[threadIdx.x], pmin[threadIdx.x + 256]);
        unsigned vmax = max(pmax[threadIdx.x], pmax[threadIdx.x + 256]);
        #pragma unroll
        for (int off = 32; off; off >>= 1){
            vmin = min(vmin, (unsigned)__shfl_down((int)vmin, off));
            vmax = max(vmax, (unsigned)__shfl_down((int)vmax, off));
        }
        int wave = threadIdx.x >> 6, lane = threadIdx.x & 63;
        if (lane == 0){ sred[wave] = vmin; sred[4+wave] = vmax; }
        __syncthreads();
        if (threadIdx.x == 0){
            sfin[0] = min(min(sred[0],sred[1]), min(sred[2],sred[3]));
            sfin[1] = max(max(sred[4],sred[5]), max(sred[6],sred[7]));
        }
        __syncthreads();
    }
    const float dmin = fdec(sfin[0]), dmax = fdec(sfin[1]);

    const int b = blockIdx.y;
    const int t = blockIdx.x*256 + threadIdx.x;        // 0 .. HW/4-1
    const int gpr = IMW/4;                             // 160 groups per row
    const int r = t / gpr;
    const int c0 = (t - r*gpr)*4;
    const float fx = Kp[b*4+0], fy = Kp[b*4+1], cx = Kp[b*4+2], cy = Kp[b*4+3];
    const float inv_fx = 1.f/fx, inv_fy = 1.f/fy;
    const float* __restrict__ d = depth1 + (size_t)b*HW;
    const int rm = max(r-1,0), rp = min(r+1,IMH-1);

    float wm[6], wc[6], wp[6];
    {
        const float* rowm = d + rm*IMW + c0;
        const float* rowc = d + r *IMW + c0;
        const float* rowp = d + rp*IMW + c0;
        float4 vm = *(const float4*)rowm;
        float4 vc = *(const float4*)rowc;
        float4 vp = *(const float4*)rowp;
        wm[1]=vm.x; wm[2]=vm.y; wm[3]=vm.z; wm[4]=vm.w;
        wc[1]=vc.x; wc[2]=vc.y; wc[3]=vc.z; wc[4]=vc.w;
        wp[1]=vp.x; wp[2]=vp.y; wp[3]=vp.z; wp[4]=vp.w;
        bool hasL = (c0 > 0), hasR = (c0+4 < IMW);
        wm[0] = hasL ? rowm[-1] : vm.x;   wm[5] = hasR ? rowm[4] : vm.w;
        wc[0] = hasL ? rowc[-1] : vc.x;   wc[5] = hasR ? rowc[4] : vc.w;
        wp[0] = hasL ? rowp[-1] : vp.x;   wp[5] = hasR ? rowp[4] : vp.w;
    }
    float pxw[6];
    #pragma unroll
    for (int k=0;k<6;k++){
        int cc = min(max(c0-1+k, 0), IMW-1);
        pxw[k] = ((float)cc - cx)*inv_fx;
    }
    const float pym = ((float)rm - cy)*inv_fy;
    const float pyc = ((float)r  - cy)*inv_fy;
    const float pyp = ((float)rp - cy)*inv_fy;

    unsigned packed[4];
    #pragma unroll
    for (int j=0;j<4;j++){
        float aL = wm[j],  aC = wm[j+1], aR = wm[j+2];
        float bL = wc[j],               bR = wc[j+2];
        float cL = wp[j],  cC = wp[j+1], cR = wp[j+2];
        float pL = pxw[j], pC = pxw[j+1], pR = pxw[j+2];

        float dx0 = (pR*aR - pL*aL) + 2.f*(pR*bR - pL*bL) + (pR*cR - pL*cL);
        float dx1 = pym*(aR - aL) + 2.f*pyc*(bR - bL) + pyp*(cR - cL);
        float dx2 = (aR - aL) + 2.f*(bR - bL) + (cR - cL);
        float dy0 = pL*(cL - aL) + 2.f*pC*(cC - aC) + pR*(cR - aR);
        float dy1 = (pyp*cL - pym*aL) + 2.f*(pyp*cC - pym*aC) + (pyp*cR - pym*aR);
        float dy2 = (cL - aL) + 2.f*(cC - aC) + (cR - aR);

        float nx = dx1*dy2 - dx2*dy1;
        float ny = dx2*dy0 - dx0*dy2;
        float nz = dx0*dy1 - dx1*dy0;
        float mag = sqrtf(nx*nx + ny*ny + nz*nz + 1e-16f);
        float inv = __builtin_amdgcn_rcpf(mag + 1e-8f);
        nx *= inv; ny *= inv; nz *= inv;

        float dc = wc[j+1];
        if (dc == dmin || dc == dmax){ nx = 0.f; ny = 0.f; nz = 0.f; }

        int qx = (int)rintf(nx*127.f) + 127;
        int qy = (int)rintf(ny*127.f) + 127;
        int qz = (int)rintf(nz*127.f) + 127;
        packed[j] = ((unsigned)qx) | ((unsigned)qy << 8) | ((unsigned)qz << 16);
    }

    size_t o4 = (size_t)b*(HW/4) + (size_t)r*gpr + (c0>>2);
    nrm4[o4] = make_uint4(packed[0], packed[1], packed[2], packed[3]);
    weights4[o4] = make_float4(1.f,1.f,1.f,1.f);
}

// ---- per-pixel ICP residual/Jacobian; GROUPS fully unrolled; 4-B texel gathers (fast path) ----
__global__ __launch_bounds__(256) void iter_kernel(const float4* __restrict__ depth0_v4,
                                                   const float* __restrict__ depth1,
                                                   const unsigned* __restrict__ nrm,
                                                   const float* __restrict__ Kp,
                                                   const float* __restrict__ stateR,
                                                   const float* __restrict__ statet,
                                                   float* __restrict__ acc){
    const int b = blockIdx.y;
    const float fx = Kp[b*4+0], fy = Kp[b*4+1], cx = Kp[b*4+2], cy = Kp[b*4+3];
    const float inv_fx = 1.f/fx, inv_fy = 1.f/fy;
    float Rm[9];
    #pragma unroll
    for (int i=0;i<9;i++) Rm[i] = stateR[b*9+i];
    float tv[3];
    #pragma unroll
    for (int i=0;i<3;i++) tv[i] = statet[b*3+i];

    const float4* __restrict__ d0v = depth0_v4 + (size_t)b*(HW/4);
    const float* __restrict__ d1   = depth1 + (size_t)b*HW;
    const unsigned* __restrict__ nb_ = nrm + (size_t)b*HW;

    float accv[27];
    #pragma unroll
    for (int i=0;i<27;i++) accv[i] = 0.f;

    const int tid = blockIdx.x*256 + threadIdx.x;     // 0..25599
    const int base0 = tid*TPX;
    const int c0 = base0 % IMW;                        // same row for all 4 px (640%4==0)
    const int r0 = base0 / IMW;
    const float px_base = ((float)c0 - cx)*inv_fx;
    const float py0 = ((float)r0 - cy)*inv_fy;
    const float py_step = (float)GROWS*inv_fy;
    const float inv127 = 1.f/127.f;

    #pragma unroll
    for (int g = 0; g < GROUPS; g++){
        float4 d4 = d0v[tid + g*THREADS_PB];
        float dd[4] = {d4.x, d4.y, d4.z, d4.w};
        float pyv = py0 + (float)g*py_step;

        #pragma unroll
        for (int j = 0; j < TPX; j++){
            float d0 = dd[j];
            float V0x = (px_base + (float)j*inv_fx)*d0;
            float V0y = pyv*d0;
            float V0z = d0;

            float X = Rm[0]*V0x + Rm[1]*V0y + Rm[2]*V0z + tv[0];
            float Y = Rm[3]*V0x + Rm[4]*V0y + Rm[5]*V0z + tv[1];
            float Z = Rm[6]*V0x + Rm[7]*V0y + Rm[8]*V0z + tv[2];
            float invZ = __builtin_amdgcn_rcpf(Z);
            float uu = X*invZ*fx + cx;
            float vv = Y*invZ*fy + cy;

            bool inview = (uu > 0.f) && (uu < (float)(IMW-1)) && (vv > 0.f) && (vv < (float)(IMH-1));

            float J0=0.f,J1=0.f,J2=0.f,J3=0.f,J4=0.f,J5=0.f,wres=0.f;
            if (inview){
                float u0f = floorf(uu), v0f = floorf(vv);
                int u0 = (int)u0f, v0 = (int)v0f;
                float wu = uu - u0f, wv = vv - v0f;
                float w00 = (1.f-wu)*(1.f-wv), w10 = wu*(1.f-wv), w01 = (1.f-wu)*wv, w11 = wu*wv;
                int i00 = v0*IMW + u0;

                float d00 = d1[i00], d10 = d1[i00+1], d01 = d1[i00+IMW], d11 = d1[i00+IMW+1];
                unsigned h00 = nb_[i00], h10 = nb_[i00+1], h01 = nb_[i00+IMW], h11 = nb_[i00+IMW+1];

                float pxa = (u0f - cx)*inv_fx, pxb = pxa + inv_fx;
                float pya = (v0f - cy)*inv_fy, pyb = pya + inv_fy;
                float a = w00*d00, bb = w10*d10, cc = w01*d01, ee = w11*d11;
                float rVz = (a + bb) + (cc + ee);
                float rVx = (a + cc)*pxa + (bb + ee)*pxb;
                float rVy = (a + bb)*pya + (cc + ee)*pyb;

                float q00x = (float)(h00 & 0xFFu);
                float q00y = (float)((h00 >> 8) & 0xFFu);
                float q00z = (float)((h00 >> 16) & 0xFFu);
                float q10x = (float)(h10 & 0xFFu);
                float q10y = (float)((h10 >> 8) & 0xFFu);
                float q10z = (float)((h10 >> 16) & 0xFFu);
                float q01x = (float)(h01 & 0xFFu);
                float q01y = (float)((h01 >> 8) & 0xFFu);
                float q01z = (float)((h01 >> 16) & 0xFFu);
                float q11x = (float)(h11 & 0xFFu);
                float q11y = (float)((h11 >> 8) & 0xFFu);
                float q11z = (float)((h11 >> 16) & 0xFFu);

                float n0x = ((w00*q00x + w10*q10x + w01*q01x + w11*q11x) - 127.f) * inv127;
                float n0y = ((w00*q00y + w10*q10y + w01*q01y + w11*q11y) - 127.f) * inv127;
                float n0z = ((w00*q00z + w10*q10z + w01*q01z + w11*q11z) - 127.f) * inv127;

                float dfx = X - rVx, dfy = Y - rVy, dfz = Z - rVz;
                float d2 = dfx*dfx + dfy*dfy + dfz*dfz + 1e-16f;
                if (d2 <= 0.01f){
                    float res = n0x*dfx + n0y*dfy + n0z*dfz;
                    float N0 = n0x*Rm[0] + n0y*Rm[3] + n0z*Rm[6];
                    float N1 = n0x*Rm[1] + n0y*Rm[4] + n0z*Rm[7];
                    float N2 = n0x*Rm[2] + n0y*Rm[5] + n0z*Rm[8];
                    float cr0 = N1*V0z - N2*V0y;
                    float cr1 = N2*V0x - N0*V0z;
                    float cr2 = N0*V0y - N1*V0x;
                    float ndot = fabsf(N2);
                    float dsh = d0 - 0.4f;
                    float sigz = 0.0012f + 0.0019f*dsh*dsh;
                    float sigma = ndot*sigz + 0.001f;
                    float invs = __builtin_amdgcn_rcpf(sigma + 1e-8f);
                    wres = res*invs;
                    J0 = -cr0*invs; J1 = -cr1*invs; J2 = -cr2*invs;
                    J3 =  N0*invs;  J4 =  N1*invs;  J5 =  N2*invs;
                }
            }

            float Jv[6] = {J0,J1,J2,J3,J4,J5};
            int idx = 0;
            #pragma unroll
            for (int k=0;k<6;k++)
                #pragma unroll
                for (int l=k;l<6;l++){ accv[idx] += Jv[k]*Jv[l]; idx++; }
            #pragma unroll
            for (int k=0;k<6;k++){ accv[idx] += Jv[k]*wres; idx++; }
        }
    }

    #pragma unroll
    for (int i=0;i<27;i++){
        float v = accv[i];
        #pragma unroll
        for (int off=32; off; off >>= 1) v += __shfl_down(v, off);
        accv[i] = v;
    }

    __shared__ float sacc[4][27];
    int wave = threadIdx.x >> 6, lane = threadIdx.x & 63;
    if (lane == 0){
        #pragma unroll
        for (int i=0;i<27;i++) sacc[wave][i] = accv[i];
    }
    __syncthreads();
    if (threadIdx.x < 27){
        float s = sacc[0][threadIdx.x] + sacc[1][threadIdx.x]
                + sacc[2][threadIdx.x] + sacc[3][threadIdx.x];
        atomicAdd(&acc[b*27 + threadIdx.x], s);
    }
}

// ---- per-batch 6x6 solve (f32 Cholesky) + twist update; prevR/prevT parameterized ----
__global__ void solve_kernel(float* __restrict__ acc,
                             const float* __restrict__ prevR, const float* __restrict__ prevT,
                             float* __restrict__ stateR, float* __restrict__ statet,
                             float* __restrict__ outR, float* __restrict__ outt){
    int b = threadIdx.x;
    if (b >= NB) return;

    float a27[27];
    #pragma unroll
    for (int i=0;i<27;i++) a27[i] = acc[b*27+i];
    #pragma unroll
    for (int i=0;i<27;i++) acc[b*27+i] = 0.f;   // zero for next iteration

    float A[6][6], rhs[6];
    int idx = 0;
    #pragma unroll
    for (int k=0;k<6;k++)
        #pragma unroll
        for (int l=k;l<6;l++){ A[k][l] = a27[idx]; A[l][k] = a27[idx]; idx++; }
    #pragma unroll
    for (int k=0;k<6;k++) rhs[k] = a27[21+k];

    float tr = 0.f;
    #pragma unroll
    for (int k=0;k<6;k++) tr += A[k][k];
    float lm = tr*1e-6f;
    #pragma unroll
    for (int k=0;k<6;k++) A[k][k] += lm;

    float L[6][6];
    #pragma unroll
    for (int i=0;i<6;i++){
        #pragma unroll
        for (int j=0;j<=i;j++){
            float s = A[i][j];
            #pragma unroll
            for (int k=0;k<j;k++) s -= L[i][k]*L[j][k];
            if (i == j) L[i][i] = sqrtf(s);
            else        L[i][j] = s / L[j][j];
        }
    }
    float y[6];
    #pragma unroll
    for (int i=0;i<6;i++){
        float s = rhs[i];
        #pragma unroll
        for (int k=0;k<i;k++) s -= L[i][k]*y[k];
        y[i] = s / L[i][i];
    }
    float xi[6];
    #pragma unroll
    for (int ii=5; ii>=0; ii--){
        float s = y[ii];
        #pragma unroll
        for (int k=ii+1;k<6;k++) s -= L[k][ii]*xi[k];
        xi[ii] = s / L[ii][ii];
    }

    float w0 = -xi[0], w1 = -xi[1], w2 = -xi[2];
    float th = sqrtf(w0*w0 + w1*w1 + w2*w2 + 1e-24f);
    float ith = 1.f/th;
    float kx = w0*ith, ky = w1*ith, kz = w2*ith;
    float s = sinf(th), cm1 = 1.f - cosf(th);
    float dRm[9];
    dRm[0] = 1.f + cm1*(-ky*ky - kz*kz);
    dRm[1] = -s*kz + cm1*(kx*ky);
    dRm[2] =  s*ky + cm1*(kx*kz);
    dRm[3] =  s*kz + cm1*(kx*ky);
    dRm[4] = 1.f + cm1*(-kx*kx - kz*kz);
    dRm[5] = -s*kx + cm1*(ky*kz);
    dRm[6] = -s*ky + cm1*(kx*kz);
    dRm[7] =  s*kx + cm1*(ky*kz);
    dRm[8] = 1.f + cm1*(-kx*kx - ky*ky);

    float dt0 = -(dRm[0]*xi[3] + dRm[1]*xi[4] + dRm[2]*xi[5]);
    float dt1 = -(dRm[3]*xi[3] + dRm[4]*xi[4] + dRm[5]*xi[5]);
    float dt2 = -(dRm[6]*xi[3] + dRm[7]*xi[4] + dRm[8]*xi[5]);

    float Rm[9], tv[3];
    #pragma unroll
    for (int i=0;i<9;i++) Rm[i] = prevR[b*9+i];
    #pragma unroll
    for (int i=0;i<3;i++) tv[i] = prevT[b*3+i];

    float Rn[9];
    #pragma unroll
    for (int i=0;i<3;i++)
        #pragma unroll
        for (int j=0;j<3;j++)
            Rn[i*3+j] = Rm[i*3+0]*dRm[0*3+j] + Rm[i*3+1]*dRm[1*3+j] + Rm[i*3+2]*dRm[2*3+j];
    float tn0 = Rm[0]*dt0 + Rm[1]*dt1 + Rm[2]*dt2 + tv[0];
    float tn1 = Rm[3]*dt0 + Rm[4]*dt1 + Rm[5]*dt2 + tv[1];
    float tn2 = Rm[6]*dt0 + Rm[7]*dt1 + Rm[8]*dt2 + tv[2];

    #pragma unroll
    for (int i=0;i<9;i++){ stateR[b*9+i] = Rn[i]; outR[b*9+i] = Rn[i]; }
    statet[b*3+0] = tn0; outt[b*3+0] = tn0;
    statet[b*3+1] = tn1; outt[b*3+1] = tn1;
    statet[b*3+2] = tn2; outt[b*3+2] = tn2;
}

extern "C" void kernel_launch(void* const* d_in, const int* in_sizes, int n_in,
                              void* d_out, int out_size, void* d_ws, size_t ws_size,
                              hipStream_t stream){
    const float* depth0 = (const float*)d_in[0];
    const float* depth1 = (const float*)d_in[1];
    const float* Kp     = (const float*)d_in[2];
    const float* Rin    = (const float*)d_in[3];
    const float* tin    = (const float*)d_in[4];

    float* out     = (float*)d_out;
    float* outR    = out;
    float* outt    = out + NB*9;
    float* weights = out + NB*12;

    unsigned* nrm  = (unsigned*)d_ws;                     // NB*HW uint (4 B/px, ~20 MB)
    unsigned* pmin = nrm + (size_t)NB*HW;                 // MMB
    unsigned* pmax = pmin + MMB;                          // MMB
    float* stateR  = (float*)(pmax + MMB);                // NB*9
    float* statet  = stateR + NB*9;                       // NB*3
    float* acc     = statet + NB*3;                       // NB*27

    minmax_kernel<<<dim3(MMB), 256, 0, stream>>>((const float4*)depth1, pmin, pmax, acc);
    normal_kernel<<<dim3(HW/4/256, NB), 256, 0, stream>>>(depth1, Kp, pmin, pmax, (uint4*)nrm, (float4*)weights);
    for (int it = 0; it < 3; it++){
        const float* Rsrc = (it == 0) ? Rin : stateR;
        const float* tsrc = (it == 0) ? tin : statet;
        iter_kernel<<<dim3(BPB, NB), 256, 0, stream>>>((const float4*)depth0, depth1, nrm, Kp, Rsrc, tsrc, acc);
        solve_kernel<<<1, 64, 0, stream>>>(acc, Rsrc, tsrc, stateR, statet, outR, outt);
    }
}